// Round 23
// baseline (181.083 us; speedup 1.0000x reference)
//
#include <hip/hip_runtime.h>
#include <hip/hip_bf16.h>

#define B_  2
#define S_  2048
#define D_  1024
#define H_  16
#define HD_ 64
#define M_  (B_*S_)   // 4096 rows of x

typedef __attribute__((ext_vector_type(8))) short short8;
typedef __attribute__((ext_vector_type(4))) float f32x4;

#define MFMA16(a, b, c) __builtin_amdgcn_mfma_f32_16x16x32_bf16((a), (b), (c), 0, 0, 0)

static __device__ inline short f2bf(float f) {
    union { float f; unsigned u; } v; v.f = f;
    unsigned r = v.u + 0x7FFFu + ((v.u >> 16) & 1u);   // round-to-nearest-even
    return (short)(r >> 16);
}

static __device__ __forceinline__ float fexp2(float x) {   // v_exp_f32 = 2^x
    float r;
    asm volatile("v_exp_f32 %0, %1\n\ts_nop 1" : "=v"(r) : "v"(x));
    return r;
}

static __device__ __forceinline__ unsigned cvt_pk_bf16(float lo, float hi) {
    unsigned r;
    asm volatile("v_cvt_pk_bf16_f32 %0, %1, %2" : "=v"(r) : "v"(lo), "v"(hi));
    return r;
}

static __device__ __forceinline__ void gl_lds16(const short* g, short* l) {
    __builtin_amdgcn_global_load_lds(
        (const __attribute__((address_space(1))) void*)g,
        (__attribute__((address_space(3))) void*)l, 16, 0, 0);
}

// ------- fused prep: z<4 -> transpose W_z to bf16 [N][K]; z==4 -> cvt x ----
__global__ void prep_kernel(const float* __restrict__ x,
                            const float* __restrict__ Wq, const float* __restrict__ Wk,
                            const float* __restrict__ Wv, const float* __restrict__ Wo,
                            short* __restrict__ xb,
                            short* __restrict__ Wqkvt, short* __restrict__ Wot) {
    int z = blockIdx.z;
    if (z == 4) {                                      // x fp32 -> bf16 (4 float4/thread)
        int bid = blockIdx.y * 32 + blockIdx.x;
        int base = bid * 1024 + threadIdx.x;
#pragma unroll
        for (int it = 0; it < 4; ++it) {
            int i = base + it * 256;
            float4 v = ((const float4*)x)[i];
            short4 o;
            o.x = f2bf(v.x); o.y = f2bf(v.y); o.z = f2bf(v.z); o.w = f2bf(v.w);
            ((short4*)xb)[i] = o;
        }
        return;
    }
    __shared__ float tile[32][33];
    const float* W = (z == 0) ? Wq : (z == 1) ? Wk : (z == 2) ? Wv : Wo;
    short* Wt = (z == 3) ? Wot : (Wqkvt + ((size_t)z << 20));
    int tx = threadIdx.x & 31, ty = threadIdx.x >> 5;   // 32x8
    int n0 = blockIdx.x * 32, k0 = blockIdx.y * 32;
#pragma unroll
    for (int i = 0; i < 4; ++i)
        tile[ty + 8 * i][tx] = W[(size_t)(k0 + ty + 8 * i) * D_ + n0 + tx];
    __syncthreads();
#pragma unroll
    for (int i = 0; i < 4; ++i)
        Wt[(size_t)(n0 + ty + 8 * i) * D_ + k0 + tx] = f2bf(tile[tx][ty + 8 * i]);
}

// ---------------- fused QKV GEMM: 128x128, A-in-registers, B-in-LDS --------
// C[M][3072] = A[M][1024] * Bt[3072][1024]^T.
// A-fragments bypass LDS: per-wave global loads straight to VGPRs, ping-pong
// prefetched one K-step ahead (named afA/afB buffers; drained by the
// top-of-step vmcnt(0)).  Each 64B A row-segment is fully consumed by the
// 4 lhi-lanes -> no overfetch.  B stays DMA-staged (r14-proven bijection):
//   chunk(row,s) = ((row>>3)<<5) | ((s^(row&3))<<3) | (row&7)
// LDS traffic per block-step: 48KB -> 24KB (was LDS-pipe bound).
// XCD-aware: XCD (bid&7) owns 3 bn-columns.  Epilogue: Q,K [b][h][s][hd];
// V^T [b][h][hd][s] (plain, no permutation).
__global__ __launch_bounds__(256) void gemm_qkv(const short* __restrict__ A,
                                                const short* __restrict__ Bt,
                                                short* __restrict__ out) {
    __shared__ __align__(16) short Bsm[2][128 * 32];   // 8 KB / buf
    const int NBX = 3;                                 // 24 bn-columns / 8 XCDs
    int X = blockIdx.x & 7, t0 = blockIdx.x >> 3;
    int bm = t0 / NBX, bn = X * NBX + t0 % NBX;
    int tid = threadIdx.x, l = tid & 63, w = tid >> 6;
    int lhi = l >> 4, llo = l & 15;
    int wm = w >> 1, wn = w & 1;

    f32x4 acc[4][4];
#pragma unroll
    for (int m = 0; m < 4; ++m)
#pragma unroll
        for (int n = 0; n < 4; ++n) acc[m][n] = (f32x4){0.f, 0.f, 0.f, 0.f};

    const short* Ag = A + (size_t)(bm * 128) * 1024;
    const short* Bg = Bt + (size_t)(bn * 128) * 1024;
    const short* Ap = Ag + (size_t)(wm * 64 + llo) * 1024 + 8 * lhi;  // lane's A base
    int c0 = tid, c1 = 256 + tid;
    int r0 = ((c0 >> 5) << 3) | (c0 & 7), s0 = ((c0 >> 3) & 3) ^ (r0 & 3);
    int r1 = ((c1 >> 5) << 3) | (c1 & 7), s1 = ((c1 >> 3) & 3) ^ (r1 & 3);

    auto stageB = [&](int buf, int k0) {
        gl_lds16(Bg + (size_t)r0 * 1024 + k0 + s0 * 8, &Bsm[buf][c0 * 8]);
        gl_lds16(Bg + (size_t)r1 * 1024 + k0 + s1 * 8, &Bsm[buf][c1 * 8]);
    };
    auto loadA = [&](short8* dst, int k0) {
#pragma unroll
        for (int m = 0; m < 4; ++m)
            dst[m] = *(const short8*)(Ap + (size_t)m * 16 * 1024 + k0);
    };

    int cib[4];
#pragma unroll
    for (int n = 0; n < 4; ++n) {
        int row = wn * 64 + n * 16 + llo;
        cib[n] = ((row >> 3) << 5) | (((lhi ^ row) & 3) << 3) | (row & 7);
    }

    auto compute = [&](const short8* af, const short* bs) {
        short8 bf[4];
#pragma unroll
        for (int n = 0; n < 4; ++n) bf[n] = *(const short8*)&bs[cib[n] * 8];
#pragma unroll
        for (int m = 0; m < 4; ++m)
#pragma unroll
            for (int n = 0; n < 4; ++n)
                acc[m][n] = MFMA16(af[m], bf[n], acc[m][n]);
    };

    short8 afA[4], afB[4];
    stageB(0, 0);
    loadA(afA, 0);
#pragma unroll 1
    for (int t = 0; t < 16; ++t) {
        // ---- step 2t: consume afA/Bsm[0]; prefetch 2t+1 into afB/Bsm[1] ----
        asm volatile("s_waitcnt vmcnt(0)" ::: "memory");
        __builtin_amdgcn_s_barrier();
        asm volatile("" ::: "memory");
        if (2 * t + 1 < 32) { stageB(1, (2 * t + 1) * 32); loadA(afB, (2 * t + 1) * 32); }
        compute(afA, Bsm[0]);
        // ---- step 2t+1: consume afB/Bsm[1]; prefetch 2t+2 into afA/Bsm[0] --
        asm volatile("s_waitcnt vmcnt(0)" ::: "memory");
        __builtin_amdgcn_s_barrier();
        asm volatile("" ::: "memory");
        if (2 * t + 2 < 32) { stageB(0, (2 * t + 2) * 32); loadA(afA, (2 * t + 2) * 32); }
        compute(afB, Bsm[1]);
    }

    int rowb = bm * 128 + wm * 64, colb = bn * 128 + wn * 64;
#pragma unroll
    for (int m = 0; m < 4; ++m) {
#pragma unroll
        for (int n = 0; n < 4; ++n) {
            int col = colb + n * 16 + llo;
#pragma unroll
            for (int j = 0; j < 4; ++j) {
                int row = rowb + m * 16 + lhi * 4 + j;
                float v = acc[m][n][j];
                int proj = col >> 10, n1 = col & 1023;
                int h = n1 >> 6, hd = n1 & 63;
                int b = row >> 11, s = row & 2047;
                size_t off;
                if (proj == 0)
                    off = ((size_t)(b * 16 + h) * 2048 + s) * 64 + hd;
                else if (proj == 1)
                    off = (size_t)M_ * D_ + ((size_t)(b * 16 + h) * 2048 + s) * 64 + hd;
                else
                    off = (size_t)2 * M_ * D_ + ((size_t)(b * 16 + h) * 64 + hd) * 2048 + s;
                out[off] = f2bf(v);
            }
        }
    }
}

// ---------------- out-proj GEMM: 64x128, A-in-registers, B-in-LDS ----------
// grid 512 (bn = bid&7, bm = bid>>3), full K, fp32 out + fused bias.
__global__ __launch_bounds__(256, 4) void gemm_out(const short* __restrict__ A,
                                                   const short* __restrict__ Bt,
                                                   const float* __restrict__ bias,
                                                   float* __restrict__ out) {
    __shared__ __align__(16) short Bsm[2][128 * 32];
    int bn = blockIdx.x & 7, bm = blockIdx.x >> 3;
    int tid = threadIdx.x, l = tid & 63, w = tid >> 6;
    int lhi = l >> 4, llo = l & 15;

    f32x4 acc[4][2];
#pragma unroll
    for (int m = 0; m < 4; ++m)
#pragma unroll
        for (int n = 0; n < 2; ++n) acc[m][n] = (f32x4){0.f, 0.f, 0.f, 0.f};

    const short* Ag = A + (size_t)(bm * 64) * 1024;
    const short* Bg = Bt + (size_t)(bn * 128) * 1024;
    const short* Ap = Ag + (size_t)llo * 1024 + 8 * lhi;
    int c0 = tid, c1 = 256 + tid;
    int r0 = ((c0 >> 5) << 3) | (c0 & 7), s0 = ((c0 >> 3) & 3) ^ (r0 & 3);
    int r1 = ((c1 >> 5) << 3) | (c1 & 7), s1 = ((c1 >> 3) & 3) ^ (r1 & 3);

    auto stageB = [&](int buf, int k0) {
        gl_lds16(Bg + (size_t)r0 * 1024 + k0 + s0 * 8, &Bsm[buf][c0 * 8]);
        gl_lds16(Bg + (size_t)r1 * 1024 + k0 + s1 * 8, &Bsm[buf][c1 * 8]);
    };
    auto loadA = [&](short8* dst, int k0) {
#pragma unroll
        for (int m = 0; m < 4; ++m)
            dst[m] = *(const short8*)(Ap + (size_t)m * 16 * 1024 + k0);
    };

    int cib[2];
#pragma unroll
    for (int n = 0; n < 2; ++n) {
        int row = w * 32 + n * 16 + llo;
        cib[n] = ((row >> 3) << 5) | (((lhi ^ row) & 3) << 3) | (row & 7);
    }

    auto compute = [&](const short8* af, const short* bs) {
        short8 bf[2];
#pragma unroll
        for (int n = 0; n < 2; ++n) bf[n] = *(const short8*)&bs[cib[n] * 8];
#pragma unroll
        for (int m = 0; m < 4; ++m)
#pragma unroll
            for (int n = 0; n < 2; ++n)
                acc[m][n] = MFMA16(af[m], bf[n], acc[m][n]);
    };

    short8 afA[4], afB[4];
    stageB(0, 0);
    loadA(afA, 0);
#pragma unroll 1
    for (int t = 0; t < 16; ++t) {
        asm volatile("s_waitcnt vmcnt(0)" ::: "memory");
        __builtin_amdgcn_s_barrier();
        asm volatile("" ::: "memory");
        if (2 * t + 1 < 32) { stageB(1, (2 * t + 1) * 32); loadA(afB, (2 * t + 1) * 32); }
        compute(afA, Bsm[0]);
        asm volatile("s_waitcnt vmcnt(0)" ::: "memory");
        __builtin_amdgcn_s_barrier();
        asm volatile("" ::: "memory");
        if (2 * t + 2 < 32) { stageB(0, (2 * t + 2) * 32); loadA(afA, (2 * t + 2) * 32); }
        compute(afB, Bsm[1]);
    }

    int rowb = bm * 64, colb = bn * 128 + w * 32;
#pragma unroll
    for (int m = 0; m < 4; ++m)
#pragma unroll
        for (int n = 0; n < 2; ++n) {
            int col = colb + n * 16 + llo;
#pragma unroll
            for (int j = 0; j < 4; ++j) {
                int row = rowb + m * 16 + lhi * 4 + j;
                out[(size_t)row * 1024 + col] = acc[m][n][j] + bias[col];
            }
        }
}

// ---------------- causal flash attention, LDS-staged double-buffered -------
// Block = 8 waves = one 128-row Q-block; grid 256 = (bh, qp in [0,8)).
// Block runs Q-block qp (2qp+2 k-tiles) then 15-qp -> uniform 34 tiles/block.
// (r18-banked version, identity V layout, 4-short P stores.)
__global__ __launch_bounds__(512) void attn_kernel(const short* __restrict__ Q,
                                                   const short* __restrict__ Kg,
                                                   const short* __restrict__ Vt,
                                                   short* __restrict__ ctx) {
    __shared__ __align__(16) char kvbuf[2][16384];   // per buf: K 8KB | V 8KB
    __shared__ __align__(16) char plds[8][2048];     // per-wave 16x64 bf16 P tile
    int tid = threadIdx.x, w = tid >> 6, l = tid & 63;
    int lhi = l >> 4, llo = l & 15;
    int bh = blockIdx.x & 31, qp = blockIdx.x >> 5;  // qp 0..7
    int b = bh >> 4, h = bh & 15;
    char* pb = plds[w];

    const short* Qh = Q + (size_t)bh * S_ * HD_;
    const short* Kh = Kg + (size_t)bh * S_ * HD_;
    const short* Vh = Vt + (size_t)bh * HD_ * S_;

    int qbA = qp, qbB = 15 - qp;
    int NTA = 2 * qp + 2;
    const int NT = 34;

    int srow = tid >> 3;
    int ssrc = (16 * (tid & 7)) ^ ((srow & 7) << 4);     // pre-swizzled byte col
    auto stage = [&](char* buf, int c0) {
        gl_lds16(Kh + (size_t)(c0 + srow) * HD_ + (ssrc >> 1), (short*)(buf + tid * 16));
        gl_lds16(Vh + (size_t)srow * S_ + c0 + (ssrc >> 1), (short*)(buf + 8192 + tid * 16));
    };

    f32x4 O[4];
#pragma unroll
    for (int n = 0; n < 4; ++n) O[n] = (f32x4){0.f, 0.f, 0.f, 0.f};
    float lpart[4] = {0.f, 0.f, 0.f, 0.f};

    auto writeOut = [&](int qb) {
        int qbs = qb * 128 + w * 16;
#pragma unroll
        for (int j = 0; j < 4; ++j) {
            float ls = lpart[j];
            ls += __shfl_xor(ls, 1);
            ls += __shfl_xor(ls, 2);
            ls += __shfl_xor(ls, 4);
            ls += __shfl_xor(ls, 8);
            float inv = 1.0f / ls;
            int row = qbs + lhi * 4 + j;
            size_t base = ((size_t)(b * S_ + row)) * D_ + h * HD_;
#pragma unroll
            for (int n = 0; n < 4; ++n)
                ctx[base + n * 16 + llo] = f2bf(O[n][j] * inv);
        }
    };

    const float SC = 0.18033688f;                    // 0.125 * log2(e)
    const float M2 = 17.312340f;                     // 12 * log2(e) (fixed max)

    int qbase = qbA * 128 + w * 16;
    short8 aq0 = *(const short8*)(Qh + (size_t)(qbase + llo) * HD_ + 8 * lhi);
    short8 aq1 = *(const short8*)(Qh + (size_t)(qbase + llo) * HD_ + 32 + 8 * lhi);

    stage(kvbuf[0], 0);

    for (int i = 0; i < NT; ++i) {
        asm volatile("s_waitcnt vmcnt(0)" ::: "memory");
        __builtin_amdgcn_s_barrier();
        asm volatile("" ::: "memory");
        int kt = (i < NTA) ? i : i - NTA;
        int c0 = kt * 64;
        if (i + 1 < NT) {
            int ni = i + 1;
            int nkt = (ni < NTA) ? ni : ni - NTA;
            stage(kvbuf[ni & 1], nkt * 64);
        }
        const char* kb = kvbuf[i & 1];
        const char* vb = kb + 8192;

        if (c0 <= qbase + 15) {
            f32x4 sc4[4];
#pragma unroll
            for (int cb = 0; cb < 4; ++cb) {
                int row = cb * 16 + llo;
                int sw = (row & 7) << 4;
                short8 kf0 = *(const short8*)(kb + row * 128 + ((16 * lhi) ^ sw));
                short8 kf1 = *(const short8*)(kb + row * 128 + ((64 + 16 * lhi) ^ sw));
                f32x4 z = (f32x4){0.f, 0.f, 0.f, 0.f};
                z = MFMA16(aq0, kf0, z);
                z = MFMA16(aq1, kf1, z);
                sc4[cb] = z;
            }
            bool diag = (c0 + 63 > qbase);
#pragma unroll
            for (int j = 0; j < 4; ++j) {
                int qr = qbase + lhi * 4 + j;
                float v0 = fmaf(sc4[0][j], SC, -M2);
                float v1 = fmaf(sc4[1][j], SC, -M2);
                float v2 = fmaf(sc4[2][j], SC, -M2);
                float v3 = fmaf(sc4[3][j], SC, -M2);
                if (diag) {
                    if (c0 + llo > qr)      v0 = -1e30f;
                    if (c0 + 16 + llo > qr) v1 = -1e30f;
                    if (c0 + 32 + llo > qr) v2 = -1e30f;
                    if (c0 + 48 + llo > qr) v3 = -1e30f;
                }
                float p0 = fexp2(v0), p1 = fexp2(v1);
                float p2 = fexp2(v2), p3 = fexp2(v3);
                lpart[j] += (p0 + p1) + (p2 + p3);
                unsigned pk01 = cvt_pk_bf16(p0, p1);
                unsigned pk23 = cvt_pk_bf16(p2, p3);
                int r = lhi * 4 + j;
                char* rb = pb + r * 128;
                int sw = (r & 7) << 4;
                *(short*)(rb + ((2 * llo) ^ sw))      = (short)(pk01);
                *(short*)(rb + ((2 * llo + 32) ^ sw)) = (short)(pk01 >> 16);
                *(short*)(rb + ((2 * llo + 64) ^ sw)) = (short)(pk23);
                *(short*)(rb + ((2 * llo + 96) ^ sw)) = (short)(pk23 >> 16);
            }
            int swr = (llo & 7) << 4;
            short8 pa0 = *(const short8*)(pb + llo * 128 + ((16 * lhi) ^ swr));
            short8 pa1 = *(const short8*)(pb + llo * 128 + ((64 + 16 * lhi) ^ swr));
#pragma unroll
            for (int n = 0; n < 4; ++n) {
                int row = n * 16 + llo;
                int sw = (row & 7) << 4;
                short8 vf0 = *(const short8*)(vb + row * 128 + ((16 * lhi) ^ sw));
                short8 vf1 = *(const short8*)(vb + row * 128 + ((64 + 16 * lhi) ^ sw));
                O[n] = MFMA16(pa0, vf0, O[n]);
                O[n] = MFMA16(pa1, vf1, O[n]);
            }
        }

        if (i == NTA - 1) {
            writeOut(qbA);
#pragma unroll
            for (int n = 0; n < 4; ++n) O[n] = (f32x4){0.f, 0.f, 0.f, 0.f};
            lpart[0] = lpart[1] = lpart[2] = lpart[3] = 0.f;
            qbase = qbB * 128 + w * 16;
            aq0 = *(const short8*)(Qh + (size_t)(qbase + llo) * HD_ + 8 * lhi);
            aq1 = *(const short8*)(Qh + (size_t)(qbase + llo) * HD_ + 32 + 8 * lhi);
        }
    }
    writeOut(qbB);
}

extern "C" void kernel_launch(void* const* d_in, const int* in_sizes, int n_in,
                              void* d_out, int out_size, void* d_ws, size_t ws_size,
                              hipStream_t stream) {
    const float* x  = (const float*)d_in[0];
    const float* Wq = (const float*)d_in[1];
    const float* Wk = (const float*)d_in[2];
    const float* Wv = (const float*)d_in[3];
    const float* Wo = (const float*)d_in[4];
    const float* bo = (const float*)d_in[5];
    float* out = (float*)d_out;

    char* ws = (char*)d_ws;
    short* xb    = (short*)(ws);                       // 8 MB (reused as ctx later)
    short* Wqkvt = (short*)(ws + (size_t)(8 << 20));   // 6 MB: [3072][1024] bf16
    short* Wot   = (short*)(ws + (size_t)(14 << 20));  // 2 MB
    short* Qb    = (short*)(ws + (size_t)(16 << 20));  // 8 MB each
    short* Kb    = Qb + (size_t)M_ * D_;
    short* Vtb   = Qb + (size_t)2 * M_ * D_;
    short* ctx   = xb;                                 // alias: xb dead after QKV GEMM

    prep_kernel<<<dim3(32, 32, 5), 256, 0, stream>>>(x, Wq, Wk, Wv, Wo, xb, Wqkvt, Wot);
    gemm_qkv<<<768, 256, 0, stream>>>(xb, Wqkvt, Qb);                      // fused QKV
    attn_kernel<<<256, 512, 0, stream>>>(Qb, Kb, Vtb, ctx);
    gemm_out<<<512, 256, 0, stream>>>(ctx, Wot, bo, out);                  // out-proj
}

// Round 24
// 161.296 us; speedup vs baseline: 1.1227x; 1.1227x over previous
//
#include <hip/hip_runtime.h>
#include <hip/hip_bf16.h>

#define B_  2
#define S_  2048
#define D_  1024
#define H_  16
#define HD_ 64
#define M_  (B_*S_)   // 4096 rows of x

typedef __attribute__((ext_vector_type(8))) short short8;
typedef __attribute__((ext_vector_type(4))) float f32x4;

#define MFMA16(a, b, c) __builtin_amdgcn_mfma_f32_16x16x32_bf16((a), (b), (c), 0, 0, 0)

static __device__ inline short f2bf(float f) {
    union { float f; unsigned u; } v; v.f = f;
    unsigned r = v.u + 0x7FFFu + ((v.u >> 16) & 1u);   // round-to-nearest-even
    return (short)(r >> 16);
}

static __device__ __forceinline__ float fexp2(float x) {   // v_exp_f32 = 2^x
    float r;
    asm volatile("v_exp_f32 %0, %1\n\ts_nop 1" : "=v"(r) : "v"(x));
    return r;
}

static __device__ __forceinline__ unsigned cvt_pk_bf16(float lo, float hi) {
    unsigned r;
    asm volatile("v_cvt_pk_bf16_f32 %0, %1, %2" : "=v"(r) : "v"(lo), "v"(hi));
    return r;
}

static __device__ __forceinline__ void gl_lds16(const short* g, short* l) {
    __builtin_amdgcn_global_load_lds(
        (const __attribute__((address_space(1))) void*)g,
        (__attribute__((address_space(3))) void*)l, 16, 0, 0);
}

// ------- fused prep: z<4 -> transpose W_z to bf16 [N][K]; z==4 -> cvt x ----
__global__ void prep_kernel(const float* __restrict__ x,
                            const float* __restrict__ Wq, const float* __restrict__ Wk,
                            const float* __restrict__ Wv, const float* __restrict__ Wo,
                            short* __restrict__ xb,
                            short* __restrict__ Wqkvt, short* __restrict__ Wot) {
    int z = blockIdx.z;
    if (z == 4) {                                      // x fp32 -> bf16 (4 float4/thread)
        int bid = blockIdx.y * 32 + blockIdx.x;
        int base = bid * 1024 + threadIdx.x;
#pragma unroll
        for (int it = 0; it < 4; ++it) {
            int i = base + it * 256;
            float4 v = ((const float4*)x)[i];
            short4 o;
            o.x = f2bf(v.x); o.y = f2bf(v.y); o.z = f2bf(v.z); o.w = f2bf(v.w);
            ((short4*)xb)[i] = o;
        }
        return;
    }
    __shared__ float tile[32][33];
    const float* W = (z == 0) ? Wq : (z == 1) ? Wk : (z == 2) ? Wv : Wo;
    short* Wt = (z == 3) ? Wot : (Wqkvt + ((size_t)z << 20));
    int tx = threadIdx.x & 31, ty = threadIdx.x >> 5;   // 32x8
    int n0 = blockIdx.x * 32, k0 = blockIdx.y * 32;
#pragma unroll
    for (int i = 0; i < 4; ++i)
        tile[ty + 8 * i][tx] = W[(size_t)(k0 + ty + 8 * i) * D_ + n0 + tx];
    __syncthreads();
#pragma unroll
    for (int i = 0; i < 4; ++i)
        Wt[(size_t)(n0 + ty + 8 * i) * D_ + k0 + tx] = f2bf(tile[tx][ty + 8 * i]);
}

// ---------------- fused QKV GEMM: 256x256, BK=64, 8-phase counted-vmcnt ----
// C[M][3072] = A[M][1024] * Bt[3072][1024]^T.  8 waves (2M x 4N), wave tile
// 128x64, acc[8][4].  LDS 128KB: [buf][A/B][half][128x64 bf16].
// Iteration i consumes K-tiles 2i (buf0, phases 0-3) and 2i+1 (buf1, 4-7);
// one half-tile staged per phase: ph0,1: buf1.A(t=2i+1); ph2,3: buf0.B(2i+2);
// ph4,5: buf0.A(2i+2); ph6,7: buf1.B(2i+3).  Every region staged >=1 phase
// after its last read (barrier-separated => WAR-safe).  vmcnt(4)+barrier at
// ph0/ph4 drains exactly the 4 half-tiles about to be consumed (RAW); never
// 0 except last-iteration ph4.  Quadrants: ph0 q(0,0), ph1 q(0,1), ph2
// q(1,1), ph3 q(1,0) (B-frag register reuse); same for buf1.
// Chunk bijection (BK=64, conflict-measured 0): c(row,s) =
//   ((row>>3)<<6) | (((s^row)&7)<<3) | (row&7),  s = 8-short col slot.
// Grid 192 = 16(bm) x 12(bn), XCD-chunked bn-major.
__global__ __launch_bounds__(512) void gemm_qkv8p(const short* __restrict__ A,
                                                  const short* __restrict__ Bt,
                                                  short* __restrict__ out) {
    __shared__ __align__(16) short lds[2][2][2][8192];  // [buf][mat][half][16KB]
    int wg = (blockIdx.x & 7) * 24 + (blockIdx.x >> 3);
    int bn = wg / 16, bm = wg % 16;
    int tid = threadIdx.x, l = tid & 63, w = tid >> 6;
    int lhi = l >> 4, llo = l & 15;
    int wm = w >> 2, wn = w & 3;
    int bh = wn >> 1;                                   // wave's B-half

    f32x4 acc[8][4];
#pragma unroll
    for (int m = 0; m < 8; ++m)
#pragma unroll
        for (int n = 0; n < 4; ++n) acc[m][n] = (f32x4){0.f, 0.f, 0.f, 0.f};

    const short* Ag = A + (size_t)(bm * 256) * 1024;
    const short* Bg = Bt + (size_t)(bn * 256) * 1024;

    // staging chunks c0 = tid, c1 = tid+512 (1024 16B-chunks per half-tile)
    int c0 = tid, c1 = tid + 512;
    int ra0 = ((c0 >> 6) << 3) | (c0 & 7), sa0 = ((c0 >> 3) & 7) ^ (ra0 & 7);
    int ra1 = ((c1 >> 6) << 3) | (c1 & 7), sa1 = ((c1 >> 3) & 7) ^ (ra1 & 7);

    auto SA = [&](int buf, int half, int t) {           // stage A half-tile
        if (t >= 16) return;
        gl_lds16(Ag + (size_t)(half * 128 + ra0) * 1024 + t * 64 + sa0 * 8,
                 &lds[buf][0][half][c0 * 8]);
        gl_lds16(Ag + (size_t)(half * 128 + ra1) * 1024 + t * 64 + sa1 * 8,
                 &lds[buf][0][half][c1 * 8]);
    };
    auto SB = [&](int buf, int half, int t) {           // stage B half-tile
        if (t >= 16) return;
        gl_lds16(Bg + (size_t)(half * 128 + ra0) * 1024 + t * 64 + sa0 * 8,
                 &lds[buf][1][half][c0 * 8]);
        gl_lds16(Bg + (size_t)(half * 128 + ra1) * 1024 + t * 64 + sa1 * 8,
                 &lds[buf][1][half][c1 * 8]);
    };

    // fragment chunk indices (K-invariant)
    auto cidx = [](int row, int s) {
        return ((row >> 3) << 6) | (((s ^ row) & 7) << 3) | (row & 7);
    };
    int cA[8][2], cB[4][2];
#pragma unroll
    for (int f = 0; f < 8; ++f)
#pragma unroll
        for (int kk = 0; kk < 2; ++kk)
            cA[f][kk] = cidx(f * 16 + llo, kk * 4 + lhi);
#pragma unroll
    for (int n = 0; n < 4; ++n)
#pragma unroll
        for (int kk = 0; kk < 2; ++kk)
            cB[n][kk] = cidx((wn & 1) * 64 + n * 16 + llo, kk * 4 + lhi);

    short8 af[8], bfE[4], bfO[4];
    auto LA = [&](int buf, int mh) {                    // 8 ds_read_b128
        const short* base = &lds[buf][0][wm][0];
#pragma unroll
        for (int mf = 0; mf < 4; ++mf)
#pragma unroll
            for (int kk = 0; kk < 2; ++kk)
                af[mf * 2 + kk] = *(const short8*)&base[cA[mh * 4 + mf][kk] * 8];
    };
    auto LB = [&](short8* bf, int buf, int nh) {        // 4 ds_read_b128
        const short* base = &lds[buf][1][bh][0];
#pragma unroll
        for (int nf = 0; nf < 2; ++nf)
#pragma unroll
            for (int kk = 0; kk < 2; ++kk)
                bf[nf * 2 + kk] = *(const short8*)&base[cB[nh * 2 + nf][kk] * 8];
    };
    auto MQ = [&](const short8* bf, int mh, int nh) {   // 16 MFMA
#pragma unroll
        for (int mf = 0; mf < 4; ++mf)
#pragma unroll
            for (int nf = 0; nf < 2; ++nf)
#pragma unroll
                for (int kk = 0; kk < 2; ++kk)
                    acc[mh * 4 + mf][nh * 2 + nf] =
                        MFMA16(af[mf * 2 + kk], bf[nf * 2 + kk],
                               acc[mh * 4 + mf][nh * 2 + nf]);
    };

#define BARRIER() do { __builtin_amdgcn_s_barrier(); asm volatile("" ::: "memory"); } while (0)

    // prologue: tile0 (buf0, 4 halves) then tile1 B (buf1) -> 12 loads
    SB(0, 0, 0); SB(0, 1, 0); SA(0, 0, 0); SA(0, 1, 0);
    SB(1, 0, 1); SB(1, 1, 1);

#pragma unroll 1
    for (int it = 0; it < 8; ++it) {
        int t1 = 2 * it + 1;
        // ---- ph0: gate buf0; q(0,0) ----
        asm volatile("s_waitcnt vmcnt(4)" ::: "memory");
        BARRIER();
        LA(0, 0); LB(bfE, 0, 0);
        SA(1, 0, t1);
        MQ(bfE, 0, 0);
        BARRIER();
        // ---- ph1: q(0,1) ----
        LB(bfO, 0, 1);
        SA(1, 1, t1);
        MQ(bfO, 0, 1);
        BARRIER();
        // ---- ph2: q(1,1) ----
        LA(0, 1);
        SB(0, 0, t1 + 1);
        MQ(bfO, 1, 1);
        BARRIER();
        // ---- ph3: q(1,0) ----
        SB(0, 1, t1 + 1);
        MQ(bfE, 1, 0);
        BARRIER();
        // ---- ph4: gate buf1; q(0,0) ----
        if (it == 7) { asm volatile("s_waitcnt vmcnt(0)" ::: "memory"); }
        else         { asm volatile("s_waitcnt vmcnt(4)" ::: "memory"); }
        BARRIER();
        LA(1, 0); LB(bfE, 1, 0);
        SA(0, 0, t1 + 1);
        MQ(bfE, 0, 0);
        BARRIER();
        // ---- ph5: q(0,1) ----
        LB(bfO, 1, 1);
        SA(0, 1, t1 + 1);
        MQ(bfO, 0, 1);
        BARRIER();
        // ---- ph6: q(1,1) ----
        LA(1, 1);
        SB(1, 0, t1 + 2);
        MQ(bfO, 1, 1);
        BARRIER();
        // ---- ph7: q(1,0) ----
        SB(1, 1, t1 + 2);
        MQ(bfE, 1, 0);
        BARRIER();
    }
#undef BARRIER

    int rowb = bm * 256 + wm * 128, colb = bn * 256 + wn * 64;
#pragma unroll
    for (int f = 0; f < 8; ++f) {
#pragma unroll
        for (int n = 0; n < 4; ++n) {
            int col = colb + n * 16 + llo;
#pragma unroll
            for (int j = 0; j < 4; ++j) {
                int row = rowb + f * 16 + lhi * 4 + j;
                float v = acc[f][n][j];
                int proj = col >> 10, n1 = col & 1023;
                int h = n1 >> 6, hd = n1 & 63;
                int b = row >> 11, s = row & 2047;
                size_t off;
                if (proj == 0)
                    off = ((size_t)(b * 16 + h) * 2048 + s) * 64 + hd;
                else if (proj == 1)
                    off = (size_t)M_ * D_ + ((size_t)(b * 16 + h) * 2048 + s) * 64 + hd;
                else
                    off = (size_t)2 * M_ * D_ + ((size_t)(b * 16 + h) * 64 + hd) * 2048 + s;
                out[off] = f2bf(v);
            }
        }
    }
}

// ---------------- out-proj GEMM: 64x128, double-buffered (r16-proven) ------
__global__ __launch_bounds__(256, 6) void gemm_out(const short* __restrict__ A,
                                                   const short* __restrict__ Bt,
                                                   const float* __restrict__ bias,
                                                   float* __restrict__ out) {
    __shared__ __align__(16) short Asm[2][64 * 32];
    __shared__ __align__(16) short Bsm[2][128 * 32];
    int bn = blockIdx.x & 7, bm = blockIdx.x >> 3;
    int tid = threadIdx.x, l = tid & 63, w = tid >> 6;
    int lhi = l >> 4, llo = l & 15;

    f32x4 acc[4][2];
#pragma unroll
    for (int m = 0; m < 4; ++m)
#pragma unroll
        for (int n = 0; n < 2; ++n) acc[m][n] = (f32x4){0.f, 0.f, 0.f, 0.f};

    const short* Ag = A + (size_t)(bm * 64) * 1024;
    const short* Bg = Bt + (size_t)(bn * 128) * 1024;
    int ca = tid;
    int ra = ((ca >> 5) << 3) | (ca & 7), sa = ((ca >> 3) & 3) ^ (ra & 3);
    int cb0 = tid, cb1 = tid + 256;
    int rb0 = ((cb0 >> 5) << 3) | (cb0 & 7), sb0 = ((cb0 >> 3) & 3) ^ (rb0 & 3);
    int rb1 = ((cb1 >> 5) << 3) | (cb1 & 7), sb1 = ((cb1 >> 3) & 3) ^ (rb1 & 3);

    auto stage = [&](int buf, int k0) {
        gl_lds16(Ag + (size_t)ra * 1024 + k0 + sa * 8, &Asm[buf][ca * 8]);
        gl_lds16(Bg + (size_t)rb0 * 1024 + k0 + sb0 * 8, &Bsm[buf][cb0 * 8]);
        gl_lds16(Bg + (size_t)rb1 * 1024 + k0 + sb1 * 8, &Bsm[buf][cb1 * 8]);
    };

    int cia[4], cib[2];
#pragma unroll
    for (int m = 0; m < 4; ++m) {
        int row = m * 16 + llo;
        cia[m] = ((row >> 3) << 5) | (((lhi ^ row) & 3) << 3) | (row & 7);
    }
#pragma unroll
    for (int n = 0; n < 2; ++n) {
        int row = w * 32 + n * 16 + llo;
        cib[n] = ((row >> 3) << 5) | (((lhi ^ row) & 3) << 3) | (row & 7);
    }

    stage(0, 0);
    for (int i = 0; i < 32; ++i) {
        asm volatile("s_waitcnt vmcnt(0)" ::: "memory");
        __builtin_amdgcn_s_barrier();
        asm volatile("" ::: "memory");
        if (i + 1 < 32) stage((i + 1) & 1, (i + 1) * 32);
        int cur = i & 1;
        short8 af[4], bf[2];
#pragma unroll
        for (int m = 0; m < 4; ++m) af[m] = *(const short8*)&Asm[cur][cia[m] * 8];
#pragma unroll
        for (int n = 0; n < 2; ++n) bf[n] = *(const short8*)&Bsm[cur][cib[n] * 8];
#pragma unroll
        for (int m = 0; m < 4; ++m)
#pragma unroll
            for (int n = 0; n < 2; ++n)
                acc[m][n] = MFMA16(af[m], bf[n], acc[m][n]);
    }

    int rowb = bm * 64, colb = bn * 128 + w * 32;
#pragma unroll
    for (int m = 0; m < 4; ++m)
#pragma unroll
        for (int n = 0; n < 2; ++n) {
            int col = colb + n * 16 + llo;
#pragma unroll
            for (int j = 0; j < 4; ++j) {
                int row = rowb + m * 16 + lhi * 4 + j;
                out[(size_t)row * 1024 + col] = acc[m][n][j] + bias[col];
            }
        }
}

// ---------------- causal flash attention, LDS-staged double-buffered -------
// (r18-banked: 8 waves, identity V layout, 4-short P stores.)
__global__ __launch_bounds__(512) void attn_kernel(const short* __restrict__ Q,
                                                   const short* __restrict__ Kg,
                                                   const short* __restrict__ Vt,
                                                   short* __restrict__ ctx) {
    __shared__ __align__(16) char kvbuf[2][16384];   // per buf: K 8KB | V 8KB
    __shared__ __align__(16) char plds[8][2048];     // per-wave 16x64 bf16 P tile
    int tid = threadIdx.x, w = tid >> 6, l = tid & 63;
    int lhi = l >> 4, llo = l & 15;
    int bh = blockIdx.x & 31, qp = blockIdx.x >> 5;  // qp 0..7
    int b = bh >> 4, h = bh & 15;
    char* pb = plds[w];

    const short* Qh = Q + (size_t)bh * S_ * HD_;
    const short* Kh = Kg + (size_t)bh * S_ * HD_;
    const short* Vh = Vt + (size_t)bh * HD_ * S_;

    int qbA = qp, qbB = 15 - qp;
    int NTA = 2 * qp + 2;
    const int NT = 34;

    int srow = tid >> 3;
    int ssrc = (16 * (tid & 7)) ^ ((srow & 7) << 4);     // pre-swizzled byte col
    auto stage = [&](char* buf, int c0) {
        gl_lds16(Kh + (size_t)(c0 + srow) * HD_ + (ssrc >> 1), (short*)(buf + tid * 16));
        gl_lds16(Vh + (size_t)srow * S_ + c0 + (ssrc >> 1), (short*)(buf + 8192 + tid * 16));
    };

    f32x4 O[4];
#pragma unroll
    for (int n = 0; n < 4; ++n) O[n] = (f32x4){0.f, 0.f, 0.f, 0.f};
    float lpart[4] = {0.f, 0.f, 0.f, 0.f};

    auto writeOut = [&](int qb) {
        int qbs = qb * 128 + w * 16;
#pragma unroll
        for (int j = 0; j < 4; ++j) {
            float ls = lpart[j];
            ls += __shfl_xor(ls, 1);
            ls += __shfl_xor(ls, 2);
            ls += __shfl_xor(ls, 4);
            ls += __shfl_xor(ls, 8);
            float inv = 1.0f / ls;
            int row = qbs + lhi * 4 + j;
            size_t base = ((size_t)(b * S_ + row)) * D_ + h * HD_;
#pragma unroll
            for (int n = 0; n < 4; ++n)
                ctx[base + n * 16 + llo] = f2bf(O[n][j] * inv);
        }
    };

    const float SC = 0.18033688f;                    // 0.125 * log2(e)
    const float M2 = 17.312340f;                     // 12 * log2(e) (fixed max)

    int qbase = qbA * 128 + w * 16;
    short8 aq0 = *(const short8*)(Qh + (size_t)(qbase + llo) * HD_ + 8 * lhi);
    short8 aq1 = *(const short8*)(Qh + (size_t)(qbase + llo) * HD_ + 32 + 8 * lhi);

    stage(kvbuf[0], 0);

    for (int i = 0; i < NT; ++i) {
        asm volatile("s_waitcnt vmcnt(0)" ::: "memory");
        __builtin_amdgcn_s_barrier();
        asm volatile("" ::: "memory");
        int kt = (i < NTA) ? i : i - NTA;
        int c0 = kt * 64;
        if (i + 1 < NT) {
            int ni = i + 1;
            int nkt = (ni < NTA) ? ni : ni - NTA;
            stage(kvbuf[ni & 1], nkt * 64);
        }
        const char* kb = kvbuf[i & 1];
        const char* vb = kb + 8192;

        if (c0 <= qbase + 15) {
            f32x4 sc4[4];
#pragma unroll
            for (int cb = 0; cb < 4; ++cb) {
                int row = cb * 16 + llo;
                int sw = (row & 7) << 4;
                short8 kf0 = *(const short8*)(kb + row * 128 + ((16 * lhi) ^ sw));
                short8 kf1 = *(const short8*)(kb + row * 128 + ((64 + 16 * lhi) ^ sw));
                f32x4 z = (f32x4){0.f, 0.f, 0.f, 0.f};
                z = MFMA16(aq0, kf0, z);
                z = MFMA16(aq1, kf1, z);
                sc4[cb] = z;
            }
            bool diag = (c0 + 63 > qbase);
#pragma unroll
            for (int j = 0; j < 4; ++j) {
                int qr = qbase + lhi * 4 + j;
                float v0 = fmaf(sc4[0][j], SC, -M2);
                float v1 = fmaf(sc4[1][j], SC, -M2);
                float v2 = fmaf(sc4[2][j], SC, -M2);
                float v3 = fmaf(sc4[3][j], SC, -M2);
                if (diag) {
                    if (c0 + llo > qr)      v0 = -1e30f;
                    if (c0 + 16 + llo > qr) v1 = -1e30f;
                    if (c0 + 32 + llo > qr) v2 = -1e30f;
                    if (c0 + 48 + llo > qr) v3 = -1e30f;
                }
                float p0 = fexp2(v0), p1 = fexp2(v1);
                float p2 = fexp2(v2), p3 = fexp2(v3);
                lpart[j] += (p0 + p1) + (p2 + p3);
                unsigned pk01 = cvt_pk_bf16(p0, p1);
                unsigned pk23 = cvt_pk_bf16(p2, p3);
                int r = lhi * 4 + j;
                char* rb = pb + r * 128;
                int sw = (r & 7) << 4;
                *(short*)(rb + ((2 * llo) ^ sw))      = (short)(pk01);
                *(short*)(rb + ((2 * llo + 32) ^ sw)) = (short)(pk01 >> 16);
                *(short*)(rb + ((2 * llo + 64) ^ sw)) = (short)(pk23);
                *(short*)(rb + ((2 * llo + 96) ^ sw)) = (short)(pk23 >> 16);
            }
            int swr = (llo & 7) << 4;
            short8 pa0 = *(const short8*)(pb + llo * 128 + ((16 * lhi) ^ swr));
            short8 pa1 = *(const short8*)(pb + llo * 128 + ((64 + 16 * lhi) ^ swr));
#pragma unroll
            for (int n = 0; n < 4; ++n) {
                int row = n * 16 + llo;
                int sw = (row & 7) << 4;
                short8 vf0 = *(const short8*)(vb + row * 128 + ((16 * lhi) ^ sw));
                short8 vf1 = *(const short8*)(vb + row * 128 + ((64 + 16 * lhi) ^ sw));
                O[n] = MFMA16(pa0, vf0, O[n]);
                O[n] = MFMA16(pa1, vf1, O[n]);
            }
        }

        if (i == NTA - 1) {
            writeOut(qbA);
#pragma unroll
            for (int n = 0; n < 4; ++n) O[n] = (f32x4){0.f, 0.f, 0.f, 0.f};
            lpart[0] = lpart[1] = lpart[2] = lpart[3] = 0.f;
            qbase = qbB * 128 + w * 16;
            aq0 = *(const short8*)(Qh + (size_t)(qbase + llo) * HD_ + 8 * lhi);
            aq1 = *(const short8*)(Qh + (size_t)(qbase + llo) * HD_ + 32 + 8 * lhi);
        }
    }
    writeOut(qbB);
}

extern "C" void kernel_launch(void* const* d_in, const int* in_sizes, int n_in,
                              void* d_out, int out_size, void* d_ws, size_t ws_size,
                              hipStream_t stream) {
    const float* x  = (const float*)d_in[0];
    const float* Wq = (const float*)d_in[1];
    const float* Wk = (const float*)d_in[2];
    const float* Wv = (const float*)d_in[3];
    const float* Wo = (const float*)d_in[4];
    const float* bo = (const float*)d_in[5];
    float* out = (float*)d_out;

    char* ws = (char*)d_ws;
    short* xb    = (short*)(ws);                       // 8 MB (reused as ctx later)
    short* Wqkvt = (short*)(ws + (size_t)(8 << 20));   // 6 MB: [3072][1024] bf16
    short* Wot   = (short*)(ws + (size_t)(14 << 20));  // 2 MB
    short* Qb    = (short*)(ws + (size_t)(16 << 20));  // 8 MB each
    short* Kb    = Qb + (size_t)M_ * D_;
    short* Vtb   = Qb + (size_t)2 * M_ * D_;
    short* ctx   = xb;                                 // alias: xb dead after QKV GEMM

    prep_kernel<<<dim3(32, 32, 5), 256, 0, stream>>>(x, Wq, Wk, Wv, Wo, xb, Wqkvt, Wot);
    gemm_qkv8p<<<192, 512, 0, stream>>>(xb, Wqkvt, Qb);                    // fused QKV
    attn_kernel<<<256, 512, 0, stream>>>(Qb, Kb, Vtb, ctx);
    gemm_out<<<512, 256, 0, stream>>>(ctx, Wot, bo, out);                  // out-proj
}

// Round 25
// 129.954 us; speedup vs baseline: 1.3934x; 1.2412x over previous
//
#include <hip/hip_runtime.h>
#include <hip/hip_bf16.h>

#define B_  2
#define S_  2048
#define D_  1024
#define H_  16
#define HD_ 64
#define M_  (B_*S_)   // 4096 rows of x

typedef __attribute__((ext_vector_type(8))) short short8;
typedef __attribute__((ext_vector_type(4))) float f32x4;

#define MFMA16(a, b, c) __builtin_amdgcn_mfma_f32_16x16x32_bf16((a), (b), (c), 0, 0, 0)

static __device__ inline short f2bf(float f) {
    union { float f; unsigned u; } v; v.f = f;
    unsigned r = v.u + 0x7FFFu + ((v.u >> 16) & 1u);   // round-to-nearest-even
    return (short)(r >> 16);
}

static __device__ __forceinline__ float fexp2(float x) {   // v_exp_f32 = 2^x
    float r;
    asm volatile("v_exp_f32 %0, %1\n\ts_nop 1" : "=v"(r) : "v"(x));
    return r;
}

static __device__ __forceinline__ unsigned cvt_pk_bf16(float lo, float hi) {
    unsigned r;
    asm volatile("v_cvt_pk_bf16_f32 %0, %1, %2" : "=v"(r) : "v"(lo), "v"(hi));
    return r;
}

static __device__ __forceinline__ void gl_lds16(const short* g, short* l) {
    __builtin_amdgcn_global_load_lds(
        (const __attribute__((address_space(1))) void*)g,
        (__attribute__((address_space(3))) void*)l, 16, 0, 0);
}

// ------- fused prep: z<4 -> transpose W_z to bf16 [N][K]; z==4 -> cvt x ----
__global__ void prep_kernel(const float* __restrict__ x,
                            const float* __restrict__ Wq, const float* __restrict__ Wk,
                            const float* __restrict__ Wv, const float* __restrict__ Wo,
                            short* __restrict__ xb,
                            short* __restrict__ Wqkvt, short* __restrict__ Wot) {
    int z = blockIdx.z;
    if (z == 4) {                                      // x fp32 -> bf16 (4 float4/thread)
        int bid = blockIdx.y * 32 + blockIdx.x;
        int base = bid * 1024 + threadIdx.x;
#pragma unroll
        for (int it = 0; it < 4; ++it) {
            int i = base + it * 256;
            float4 v = ((const float4*)x)[i];
            short4 o;
            o.x = f2bf(v.x); o.y = f2bf(v.y); o.z = f2bf(v.z); o.w = f2bf(v.w);
            ((short4*)xb)[i] = o;
        }
        return;
    }
    __shared__ float tile[32][33];
    const float* W = (z == 0) ? Wq : (z == 1) ? Wk : (z == 2) ? Wv : Wo;
    short* Wt = (z == 3) ? Wot : (Wqkvt + ((size_t)z << 20));
    int tx = threadIdx.x & 31, ty = threadIdx.x >> 5;   // 32x8
    int n0 = blockIdx.x * 32, k0 = blockIdx.y * 32;
#pragma unroll
    for (int i = 0; i < 4; ++i)
        tile[ty + 8 * i][tx] = W[(size_t)(k0 + ty + 8 * i) * D_ + n0 + tx];
    __syncthreads();
#pragma unroll
    for (int i = 0; i < 4; ++i)
        Wt[(size_t)(n0 + ty + 8 * i) * D_ + k0 + tx] = f2bf(tile[tx][ty + 8 * i]);
}

// ---------------- fused QKV GEMM: 128x128, double-buffered (r14/r18-proven) -
// C[M][3072] = A[M][1024] * Bt[3072][1024]^T.  Stage(i+1) issued after the
// top vmcnt(0)+barrier of step i.  LDS chunk bijection (conflict-free):
//   chunk(row,s) = ((row>>3)<<5) | ((s^(row&3))<<3) | (row&7)
// XCD-aware: XCD (bid&7) owns 3 bn-columns (B-panels L2-resident).
// Epilogue: Q,K [b][h][s][hd]; V^T [b][h][hd][s] (plain layout).
__global__ __launch_bounds__(256) void gemm_qkv(const short* __restrict__ A,
                                                const short* __restrict__ Bt,
                                                short* __restrict__ out) {
    __shared__ __align__(16) short Asm[2][128 * 32];
    __shared__ __align__(16) short Bsm[2][128 * 32];
    const int NBX = 3;                                 // 24 bn-columns / 8 XCDs
    int X = blockIdx.x & 7, t = blockIdx.x >> 3;
    int bm = t / NBX, bn = X * NBX + t % NBX;
    int tid = threadIdx.x, l = tid & 63, w = tid >> 6;
    int lhi = l >> 4, llo = l & 15;
    int wm = w >> 1, wn = w & 1;

    f32x4 acc[4][4];
#pragma unroll
    for (int m = 0; m < 4; ++m)
#pragma unroll
        for (int n = 0; n < 4; ++n) acc[m][n] = (f32x4){0.f, 0.f, 0.f, 0.f};

    const short* Ag = A + (size_t)(bm * 128) * 1024;
    const short* Bg = Bt + (size_t)(bn * 128) * 1024;
    int c0 = tid, c1 = 256 + tid;
    int r0 = ((c0 >> 5) << 3) | (c0 & 7), s0 = ((c0 >> 3) & 3) ^ (r0 & 3);
    int r1 = ((c1 >> 5) << 3) | (c1 & 7), s1 = ((c1 >> 3) & 3) ^ (r1 & 3);

    auto stage = [&](int buf, int k0) {
        gl_lds16(Ag + (size_t)r0 * 1024 + k0 + s0 * 8, &Asm[buf][c0 * 8]);
        gl_lds16(Ag + (size_t)r1 * 1024 + k0 + s1 * 8, &Asm[buf][c1 * 8]);
        gl_lds16(Bg + (size_t)r0 * 1024 + k0 + s0 * 8, &Bsm[buf][c0 * 8]);
        gl_lds16(Bg + (size_t)r1 * 1024 + k0 + s1 * 8, &Bsm[buf][c1 * 8]);
    };

    int cia[4], cib[4];
#pragma unroll
    for (int m = 0; m < 4; ++m) {
        int row = wm * 64 + m * 16 + llo;
        cia[m] = ((row >> 3) << 5) | (((lhi ^ row) & 3) << 3) | (row & 7);
    }
#pragma unroll
    for (int n = 0; n < 4; ++n) {
        int row = wn * 64 + n * 16 + llo;
        cib[n] = ((row >> 3) << 5) | (((lhi ^ row) & 3) << 3) | (row & 7);
    }

    stage(0, 0);
    for (int i = 0; i < 32; ++i) {
        asm volatile("s_waitcnt vmcnt(0)" ::: "memory");
        __builtin_amdgcn_s_barrier();
        asm volatile("" ::: "memory");
        if (i + 1 < 32) stage((i + 1) & 1, (i + 1) * 32);
        int cur = i & 1;
        short8 af[4], bf[4];
#pragma unroll
        for (int m = 0; m < 4; ++m) af[m] = *(const short8*)&Asm[cur][cia[m] * 8];
#pragma unroll
        for (int n = 0; n < 4; ++n) bf[n] = *(const short8*)&Bsm[cur][cib[n] * 8];
#pragma unroll
        for (int m = 0; m < 4; ++m)
#pragma unroll
            for (int n = 0; n < 4; ++n)
                acc[m][n] = MFMA16(af[m], bf[n], acc[m][n]);
    }

    int rowb = bm * 128 + wm * 64, colb = bn * 128 + wn * 64;
#pragma unroll
    for (int m = 0; m < 4; ++m) {
#pragma unroll
        for (int n = 0; n < 4; ++n) {
            int col = colb + n * 16 + llo;
#pragma unroll
            for (int j = 0; j < 4; ++j) {
                int row = rowb + m * 16 + lhi * 4 + j;
                float v = acc[m][n][j];
                int proj = col >> 10, n1 = col & 1023;
                int h = n1 >> 6, hd = n1 & 63;
                int b = row >> 11, s = row & 2047;
                size_t off;
                if (proj == 0)
                    off = ((size_t)(b * 16 + h) * 2048 + s) * 64 + hd;
                else if (proj == 1)
                    off = (size_t)M_ * D_ + ((size_t)(b * 16 + h) * 2048 + s) * 64 + hd;
                else
                    off = (size_t)2 * M_ * D_ + ((size_t)(b * 16 + h) * 64 + hd) * 2048 + s;
                out[off] = f2bf(v);
            }
        }
    }
}

// ---------------- out-proj GEMM: 64x128, double-buffered (r16-proven) ------
__global__ __launch_bounds__(256, 6) void gemm_out(const short* __restrict__ A,
                                                   const short* __restrict__ Bt,
                                                   const float* __restrict__ bias,
                                                   float* __restrict__ out) {
    __shared__ __align__(16) short Asm[2][64 * 32];
    __shared__ __align__(16) short Bsm[2][128 * 32];
    int bn = blockIdx.x & 7, bm = blockIdx.x >> 3;
    int tid = threadIdx.x, l = tid & 63, w = tid >> 6;
    int lhi = l >> 4, llo = l & 15;

    f32x4 acc[4][2];
#pragma unroll
    for (int m = 0; m < 4; ++m)
#pragma unroll
        for (int n = 0; n < 2; ++n) acc[m][n] = (f32x4){0.f, 0.f, 0.f, 0.f};

    const short* Ag = A + (size_t)(bm * 64) * 1024;
    const short* Bg = Bt + (size_t)(bn * 128) * 1024;
    int ca = tid;
    int ra = ((ca >> 5) << 3) | (ca & 7), sa = ((ca >> 3) & 3) ^ (ra & 3);
    int cb0 = tid, cb1 = tid + 256;
    int rb0 = ((cb0 >> 5) << 3) | (cb0 & 7), sb0 = ((cb0 >> 3) & 3) ^ (rb0 & 3);
    int rb1 = ((cb1 >> 5) << 3) | (cb1 & 7), sb1 = ((cb1 >> 3) & 3) ^ (rb1 & 3);

    auto stage = [&](int buf, int k0) {
        gl_lds16(Ag + (size_t)ra * 1024 + k0 + sa * 8, &Asm[buf][ca * 8]);
        gl_lds16(Bg + (size_t)rb0 * 1024 + k0 + sb0 * 8, &Bsm[buf][cb0 * 8]);
        gl_lds16(Bg + (size_t)rb1 * 1024 + k0 + sb1 * 8, &Bsm[buf][cb1 * 8]);
    };

    int cia[4], cib[2];
#pragma unroll
    for (int m = 0; m < 4; ++m) {
        int row = m * 16 + llo;
        cia[m] = ((row >> 3) << 5) | (((lhi ^ row) & 3) << 3) | (row & 7);
    }
#pragma unroll
    for (int n = 0; n < 2; ++n) {
        int row = w * 32 + n * 16 + llo;
        cib[n] = ((row >> 3) << 5) | (((lhi ^ row) & 3) << 3) | (row & 7);
    }

    stage(0, 0);
    for (int i = 0; i < 32; ++i) {
        asm volatile("s_waitcnt vmcnt(0)" ::: "memory");
        __builtin_amdgcn_s_barrier();
        asm volatile("" ::: "memory");
        if (i + 1 < 32) stage((i + 1) & 1, (i + 1) * 32);
        int cur = i & 1;
        short8 af[4], bf[2];
#pragma unroll
        for (int m = 0; m < 4; ++m) af[m] = *(const short8*)&Asm[cur][cia[m] * 8];
#pragma unroll
        for (int n = 0; n < 2; ++n) bf[n] = *(const short8*)&Bsm[cur][cib[n] * 8];
#pragma unroll
        for (int m = 0; m < 4; ++m)
#pragma unroll
            for (int n = 0; n < 2; ++n)
                acc[m][n] = MFMA16(af[m], bf[n], acc[m][n]);
    }

    int rowb = bm * 64, colb = bn * 128 + w * 32;
#pragma unroll
    for (int m = 0; m < 4; ++m)
#pragma unroll
        for (int n = 0; n < 2; ++n) {
            int col = colb + n * 16 + llo;
#pragma unroll
            for (int j = 0; j < 4; ++j) {
                int row = rowb + m * 16 + lhi * 4 + j;
                out[(size_t)row * 1024 + col] = acc[m][n][j] + bias[col];
            }
        }
}

// ---------------- causal flash attention, k-tile = 128 ---------------------
// Block = 8 waves x 16 q-rows = one 128-row Q-block; grid 256 = (bh, qp).
// Block runs Q-block qp (qp+1 k-tiles of 128) then 15-qp (16-qp tiles) ->
// uniform 17 tiles/block; HALF the barrier/drain rounds of the 64-wide form.
// K tile [128k][64hd] (128B rows, swizzle (row&7)<<4); V^T tile [64hd][128k]
// (256B rows, swizzle (row&15)<<4 -> 2-way reads).  P = two 16x64 half-tiles
// per wave (byte-identical to the proven 64-wide layout).
__global__ __launch_bounds__(512) void attn_kernel(const short* __restrict__ Q,
                                                   const short* __restrict__ Kg,
                                                   const short* __restrict__ Vt,
                                                   short* __restrict__ ctx) {
    __shared__ __align__(16) char kvbuf[2][32768];   // per buf: K 16KB | V 16KB
    __shared__ __align__(16) char plds[8][2][2048];  // per-wave 2 x (16x64) P
    int tid = threadIdx.x, w = tid >> 6, l = tid & 63;
    int lhi = l >> 4, llo = l & 15;
    int bh = blockIdx.x & 31, qp = blockIdx.x >> 5;  // qp 0..7
    int b = bh >> 4, h = bh & 15;
    char* pb0 = plds[w][0];
    char* pb1 = plds[w][1];

    const short* Qh = Q + (size_t)bh * S_ * HD_;
    const short* Kh = Kg + (size_t)bh * S_ * HD_;
    const short* Vh = Vt + (size_t)bh * HD_ * S_;

    int qbA = qp, qbB = 15 - qp;
    int NTA = qp + 1;
    const int NT = 17;                               // (qp+1) + (16-qp)

    // staging: 512 thr x (2 K-chunks + 2 V-chunks) of 16B = 16KB + 16KB
    auto stage = [&](char* buf, int c0) {
#pragma unroll
        for (int i2 = 0; i2 < 2; ++i2) {
            int cc = tid + 512 * i2;                 // 0..1023
            int kr = cc >> 3, ks = (16 * (cc & 7)) ^ ((kr & 7) << 4);
            gl_lds16(Kh + (size_t)(c0 + kr) * HD_ + (ks >> 1), (short*)(buf + cc * 16));
            int vr = cc >> 4, vs = (16 * (cc & 15)) ^ ((vr & 15) << 4);
            gl_lds16(Vh + (size_t)vr * S_ + c0 + (vs >> 1),
                     (short*)(buf + 16384 + cc * 16));
        }
    };

    f32x4 O[4];
#pragma unroll
    for (int n = 0; n < 4; ++n) O[n] = (f32x4){0.f, 0.f, 0.f, 0.f};
    float lpart[4] = {0.f, 0.f, 0.f, 0.f};

    auto writeOut = [&](int qb) {
        int qbs = qb * 128 + w * 16;
#pragma unroll
        for (int j = 0; j < 4; ++j) {
            float ls = lpart[j];
            ls += __shfl_xor(ls, 1);
            ls += __shfl_xor(ls, 2);
            ls += __shfl_xor(ls, 4);
            ls += __shfl_xor(ls, 8);
            float inv = 1.0f / ls;
            int row = qbs + lhi * 4 + j;
            size_t base = ((size_t)(b * S_ + row)) * D_ + h * HD_;
#pragma unroll
            for (int n = 0; n < 4; ++n)
                ctx[base + n * 16 + llo] = f2bf(O[n][j] * inv);
        }
    };

    const float SC = 0.18033688f;                    // 0.125 * log2(e)
    const float M2 = 17.312340f;                     // 12 * log2(e) (fixed max)

    int qbase = qbA * 128 + w * 16;
    short8 aq0 = *(const short8*)(Qh + (size_t)(qbase + llo) * HD_ + 8 * lhi);
    short8 aq1 = *(const short8*)(Qh + (size_t)(qbase + llo) * HD_ + 32 + 8 * lhi);

    stage(kvbuf[0], 0);

    for (int i = 0; i < NT; ++i) {
        asm volatile("s_waitcnt vmcnt(0)" ::: "memory");
        __builtin_amdgcn_s_barrier();
        asm volatile("" ::: "memory");
        int kt = (i < NTA) ? i : i - NTA;
        int c0 = kt * 128;
        if (i + 1 < NT) {
            int ni = i + 1;
            int nkt = (ni < NTA) ? ni : ni - NTA;
            stage(kvbuf[ni & 1], nkt * 128);
        }
        const char* kb = kvbuf[i & 1];
        const char* vb = kb + 16384;

        if (c0 <= qbase + 15) {
            // ---- QK^T: 8 col-blocks of 16 k ----
            f32x4 sc4[8];
#pragma unroll
            for (int cb = 0; cb < 8; ++cb) {
                int row = cb * 16 + llo;
                int sw = (row & 7) << 4;
                short8 kf0 = *(const short8*)(kb + row * 128 + ((16 * lhi) ^ sw));
                short8 kf1 = *(const short8*)(kb + row * 128 + ((64 + 16 * lhi) ^ sw));
                f32x4 z = (f32x4){0.f, 0.f, 0.f, 0.f};
                z = MFMA16(aq0, kf0, z);
                z = MFMA16(aq1, kf1, z);
                sc4[cb] = z;
            }
            // ---- fixed-max softmax, two P half-tiles ----
            bool diag = (c0 + 127 > qbase);          // only the true diagonal tile
#pragma unroll
            for (int j = 0; j < 4; ++j) {
                int qr = qbase + lhi * 4 + j;
                float p[8];
#pragma unroll
                for (int cb = 0; cb < 8; ++cb) {
                    float v = fmaf(sc4[cb][j], SC, -M2);
                    if (diag && (c0 + cb * 16 + llo > qr)) v = -1e30f;
                    p[cb] = fexp2(v);
                }
                lpart[j] += ((p[0] + p[1]) + (p[2] + p[3])) +
                            ((p[4] + p[5]) + (p[6] + p[7]));
                int r = lhi * 4 + j;
                int sw = (r & 7) << 4;
                unsigned pkA = cvt_pk_bf16(p[0], p[1]);
                unsigned pkB = cvt_pk_bf16(p[2], p[3]);
                char* rb = pb0 + r * 128;
                *(short*)(rb + ((2 * llo) ^ sw))      = (short)(pkA);
                *(short*)(rb + ((2 * llo + 32) ^ sw)) = (short)(pkA >> 16);
                *(short*)(rb + ((2 * llo + 64) ^ sw)) = (short)(pkB);
                *(short*)(rb + ((2 * llo + 96) ^ sw)) = (short)(pkB >> 16);
                unsigned pkC = cvt_pk_bf16(p[4], p[5]);
                unsigned pkD = cvt_pk_bf16(p[6], p[7]);
                rb = pb1 + r * 128;
                *(short*)(rb + ((2 * llo) ^ sw))      = (short)(pkC);
                *(short*)(rb + ((2 * llo + 32) ^ sw)) = (short)(pkC >> 16);
                *(short*)(rb + ((2 * llo + 64) ^ sw)) = (short)(pkD);
                *(short*)(rb + ((2 * llo + 96) ^ sw)) = (short)(pkD >> 16);
            }
            // ---- PV: 4 k-chunks of 32 ----
            int swr = (llo & 7) << 4;
            short8 pa[4];
            pa[0] = *(const short8*)(pb0 + llo * 128 + ((16 * lhi) ^ swr));
            pa[1] = *(const short8*)(pb0 + llo * 128 + ((64 + 16 * lhi) ^ swr));
            pa[2] = *(const short8*)(pb1 + llo * 128 + ((16 * lhi) ^ swr));
            pa[3] = *(const short8*)(pb1 + llo * 128 + ((64 + 16 * lhi) ^ swr));
#pragma unroll
            for (int n = 0; n < 4; ++n) {
                int vrow = n * 16 + llo;
                int vsw = (vrow & 15) << 4;
#pragma unroll
                for (int kc = 0; kc < 4; ++kc) {
                    short8 vf = *(const short8*)(vb + vrow * 256 +
                                                 ((kc * 64 + 16 * lhi) ^ vsw));
                    O[n] = MFMA16(pa[kc], vf, O[n]);
                }
            }
        }

        if (i == NTA - 1) {                          // phase A done
            writeOut(qbA);
#pragma unroll
            for (int n = 0; n < 4; ++n) O[n] = (f32x4){0.f, 0.f, 0.f, 0.f};
            lpart[0] = lpart[1] = lpart[2] = lpart[3] = 0.f;
            qbase = qbB * 128 + w * 16;
            aq0 = *(const short8*)(Qh + (size_t)(qbase + llo) * HD_ + 8 * lhi);
            aq1 = *(const short8*)(Qh + (size_t)(qbase + llo) * HD_ + 32 + 8 * lhi);
        }
    }
    writeOut(qbB);
}

extern "C" void kernel_launch(void* const* d_in, const int* in_sizes, int n_in,
                              void* d_out, int out_size, void* d_ws, size_t ws_size,
                              hipStream_t stream) {
    const float* x  = (const float*)d_in[0];
    const float* Wq = (const float*)d_in[1];
    const float* Wk = (const float*)d_in[2];
    const float* Wv = (const float*)d_in[3];
    const float* Wo = (const float*)d_in[4];
    const float* bo = (const float*)d_in[5];
    float* out = (float*)d_out;

    char* ws = (char*)d_ws;
    short* xb    = (short*)(ws);                       // 8 MB (reused as ctx later)
    short* Wqkvt = (short*)(ws + (size_t)(8 << 20));   // 6 MB: [3072][1024] bf16
    short* Wot   = (short*)(ws + (size_t)(14 << 20));  // 2 MB
    short* Qb    = (short*)(ws + (size_t)(16 << 20));  // 8 MB each
    short* Kb    = Qb + (size_t)M_ * D_;
    short* Vtb   = Qb + (size_t)2 * M_ * D_;
    short* ctx   = xb;                                 // alias: xb dead after QKV GEMM

    prep_kernel<<<dim3(32, 32, 5), 256, 0, stream>>>(x, Wq, Wk, Wv, Wo, xb, Wqkvt, Wot);
    gemm_qkv<<<768, 256, 0, stream>>>(xb, Wqkvt, Qb);                      // fused QKV
    attn_kernel<<<256, 512, 0, stream>>>(Qb, Kb, Vtb, ctx);
    gemm_out<<<512, 256, 0, stream>>>(ctx, Wot, bo, out);                  // out-proj
}